// Round 9
// baseline (1001.947 us; speedup 1.0000x reference)
//
#include <hip/hip_runtime.h>
#include <cstdint>
#include <cstddef>

#define B_      4
#define N_      10000
#define E_      320000
#define FN_     16
#define EOUT    64
#define NHID    12
#define CH      16
#define NCHUNK  625   // ceil(10000/16)
#define HB      250
#define EPB     1280
#define SENTX   (16u << 20)

typedef _Float16 v8h __attribute__((ext_vector_type(8)));
typedef float    v4f __attribute__((ext_vector_type(4)));

// RTN pack of two floats into packed-f16 dword (proven numerics, rounds 4/5/8)
__device__ __forceinline__ uint32_t pkh(float a, float b) {
    _Float16 lo = (_Float16)a, hi = (_Float16)b;
    uint32_t ul = (uint32_t)__builtin_bit_cast(uint16_t, lo);
    uint32_t uh = (uint32_t)__builtin_bit_cast(uint16_t, hi);
    return ul | (uh << 16);
}
__device__ __forceinline__ v8h mkv8h(uint32_t a, uint32_t b, uint32_t c, uint32_t d) {
    uint4 t = make_uint4(a, b, c, d);
    return __builtin_bit_cast(v8h, t);
}

// ---------------- prepasses ----------------

__global__ __launch_bounds__(256) void hist_kernel(
    const int* __restrict__ esrc, const int* __restrict__ etgt,
    int* __restrict__ counts)
{
    __shared__ int hc[NCHUNK];
    const int tid = threadIdx.x;
    for (int i = tid; i < NCHUNK; i += 256) hc[i] = 0;
    __syncthreads();
    const int e0 = blockIdx.x * EPB;
    #pragma unroll
    for (int k = 0; k < EPB / 256; k++) {
        const int e = e0 + k * 256 + tid;
        atomicAdd(&hc[esrc[e] >> 4], 1);
        atomicAdd(&hc[etgt[e] >> 4], 1);
    }
    __syncthreads();
    for (int i = tid; i < NCHUNK; i += 256)
        if (hc[i]) atomicAdd(&counts[i], hc[i]);
}

__global__ __launch_bounds__(1024) void scan_kernel(
    const int* __restrict__ counts,
    int* __restrict__ offsets, int* __restrict__ cursors)
{
    __shared__ int s[1024];
    const int tid = threadIdx.x;
    s[tid] = (tid < NCHUNK) ? counts[tid] : 0;
    __syncthreads();
    #pragma unroll
    for (int off = 1; off < 1024; off <<= 1) {
        int v = (tid >= off) ? s[tid - off] : 0;
        __syncthreads();
        s[tid] += v;
        __syncthreads();
    }
    if (tid < NCHUNK) {
        int excl = (tid == 0) ? 0 : s[tid - 1];
        offsets[tid] = excl;
        cursors[tid] = excl;
    }
    if (tid == 0) offsets[NCHUNK] = s[NCHUNK - 1];
}

__global__ __launch_bounds__(256) void fill_kernel(
    const int* __restrict__ esrc, const int* __restrict__ etgt,
    int* __restrict__ cursors, uint2* __restrict__ entries)
{
    __shared__ int hc[NCHUNK];
    __shared__ int base_[NCHUNK];
    const int tid = threadIdx.x;
    for (int i = tid; i < NCHUNK; i += 256) hc[i] = 0;
    __syncthreads();
    const int e0 = blockIdx.x * EPB;
    #pragma unroll
    for (int k = 0; k < EPB / 256; k++) {
        const int e = e0 + k * 256 + tid;
        atomicAdd(&hc[esrc[e] >> 4], 1);
        atomicAdd(&hc[etgt[e] >> 4], 1);
    }
    __syncthreads();
    for (int i = tid; i < NCHUNK; i += 256) {
        if (hc[i] > 0) {
            base_[i] = atomicAdd(&cursors[i], hc[i]);
            hc[i] = 0;
        }
    }
    __syncthreads();
    #pragma unroll
    for (int k = 0; k < EPB / 256; k++) {
        const int e = e0 + k * 256 + tid;
        const int s = esrc[e], t = etgt[e];
        const int cs = s >> 4, ct = t >> 4;
        int p = base_[cs] + atomicAdd(&hc[cs], 1);
        entries[p] = make_uint2((unsigned)e | (1u << 19) | ((unsigned)(s & 15) << 20), (unsigned)t);
        p = base_[ct] + atomicAdd(&hc[ct], 1);
        entries[p] = make_uint2((unsigned)e | ((unsigned)(t & 15) << 20), (unsigned)s);
    }
}

// ---------------- fused chunk kernel (round-8 engine + occupancy/ILP2) ----------------

struct TS { float4 q0, q1; float w, sgn; int own; };

__device__ __forceinline__ void decode_entry(uint2 ent, int node0, int g,
                                             int& node, int& own, float& sgn, int& eidx)
{
    eidx = (int)(ent.x & 0x7FFFFu);
    const int isSrc = (int)((ent.x >> 19) & 1u);
    own = (int)((ent.x >> 20) & 31u);            // 0..15, sentinel 16
    const int own_g = min(node0 + own, N_ - 1);
    const int other = (int)ent.y;
    const int srcn = isSrc ? own_g : other;
    const int tgtn = isSrc ? other : own_g;
    node = (g < 2) ? srcn : tgtn;
    sgn = isSrc ? -1.f : 1.f;
}

__global__ __launch_bounds__(256, 4) void chunk_kernel(
    const float* __restrict__ nf,      // [B][N][16]
    const float* __restrict__ ew,      // [B][E]
    const float* __restrict__ lp,      // [B][N]
    const uint2* __restrict__ entries,
    const int*   __restrict__ offsets,
    const float* __restrict__ W1, const float* __restrict__ b1,
    const float* __restrict__ W2, const float* __restrict__ b2,
    const float* __restrict__ W3, const float* __restrict__ b3,
    const float* __restrict__ W4, const float* __restrict__ b4,
    const float* __restrict__ W5, const float* __restrict__ b5,
    float* __restrict__ out)           // [B][N]
{
    __shared__ float sagg[CH + 1][67];           // stride 67: own*67 mod 32 distinct
    __shared__ float sFold[4][4][8];             // [mt][g][W1row32 x4 | b1 x4]
    __shared__ float sb2f[2][4][4];              // [mt][g][r]
    __shared__ float sb3f[4][4][4];
    __shared__ float sW4[(EOUT + 1) * NHID];
    __shared__ float sb4[NHID];
    __shared__ float sW5[NHID];
    __shared__ float sb5v;

    const int tid   = threadIdx.x;
    const int c     = blockIdx.x;
    const int b     = blockIdx.y;
    const int node0 = c * CH;
    const int nvalid = min(CH, N_ - node0);

    for (int i = tid; i < (EOUT + 1) * NHID; i += 256) sW4[i] = W4[i];
    if (tid < NHID) { sb4[tid] = b4[tid]; sW5[tid] = W5[tid]; }
    if (tid == 0) sb5v = b5[0];
    if (tid < 64) {   // sFold: ch = 16*mt + 4*g + r
        const int mt = tid >> 4, gg = (tid >> 2) & 3, r = tid & 3;
        const int ch = 16 * mt + 4 * gg + r;
        sFold[mt][gg][r]     = W1[32 * 64 + ch];
        sFold[mt][gg][4 + r] = b1[ch];
    }
    if (tid >= 64 && tid < 96) {   // sb2f
        const int t = tid - 64;
        const int mt = t >> 4, gg = (t >> 2) & 3, r = t & 3;
        sb2f[mt][gg][r] = b2[16 * mt + 4 * gg + r];
    }
    if (tid >= 128 && tid < 192) { // sb3f
        const int t = tid - 128;
        const int mt = t >> 4, gg = (t >> 2) & 3, r = t & 3;
        sb3f[mt][gg][r] = b3[16 * mt + 4 * gg + r];
    }
    {
        float* sa = &sagg[0][0];
        for (int i = tid; i < (CH + 1) * 67; i += 256) sa[i] = 0.f;
    }

    const int wv = tid >> 6, ln = tid & 63;
    const int g  = ln >> 4;            // k-group 0..3
    const int cl = ln & 15;            // edge-in-tile

    // ---- persistent register weight fragments (A-operand = W^T) ----
    v8h A0w1[4], A0w2[2], A1w2[2], A0w3[4];
    #pragma unroll
    for (int mt = 0; mt < 4; mt++) {
        const int och = 16 * mt + cl;
        float f[8];
        #pragma unroll
        for (int j = 0; j < 8; j++) f[j] = W1[(8 * g + j) * 64 + och];
        A0w1[mt] = mkv8h(pkh(f[0],f[1]), pkh(f[2],f[3]), pkh(f[4],f[5]), pkh(f[6],f[7]));
    }
    #pragma unroll
    for (int mt = 0; mt < 2; mt++) {
        const int och = 16 * mt + cl;
        float f[8];
        #pragma unroll
        for (int j = 0; j < 8; j++) f[j] = W2[(8 * g + j) * 32 + och];
        A0w2[mt] = mkv8h(pkh(f[0],f[1]), pkh(f[2],f[3]), pkh(f[4],f[5]), pkh(f[6],f[7]));
        #pragma unroll
        for (int j = 0; j < 8; j++) f[j] = W2[(32 + 8 * g + j) * 32 + och];
        A1w2[mt] = mkv8h(pkh(f[0],f[1]), pkh(f[2],f[3]), pkh(f[4],f[5]), pkh(f[6],f[7]));
    }
    #pragma unroll
    for (int mt = 0; mt < 4; mt++) {
        const int och = 16 * mt + cl;
        float f[8];
        #pragma unroll
        for (int j = 0; j < 8; j++) f[j] = W3[(8 * g + j) * 64 + och];
        A0w3[mt] = mkv8h(pkh(f[0],f[1]), pkh(f[2],f[3]), pkh(f[4],f[5]), pkh(f[6],f[7]));
    }

    __syncthreads();

    const int beg = offsets[c], end = offsets[c + 1];
    const int a1 = (32 * (g & 1) + cl) * 4;      // bpermute src lane g'' = 2*(g&1)
    const int a2 = a1 + 64;                      // src lane g'' = 2*(g&1)+1
    const bool glo = (g < 2);
    const float* nfB = nf + (size_t)b * N_ * FN_;
    const float* ewB = ew + (size_t)b * E_;

    auto fetch_raw = [&](int t) -> uint2 {       // t = tile start (wave-uniform)
        if (t < end) return entries[min(t + cl, end - 1)];
        return make_uint2(SENTX, 0u);
    };
    auto stage = [&](uint2 raw, int t) -> TS {
        TS s;
        uint2 ent = raw;
        if (t + cl >= end) ent = make_uint2(SENTX, 0u);
        int node, eidx;
        decode_entry(ent, node0, g, node, s.own, s.sgn, eidx);
        const float* p = nfB + (size_t)node * FN_ + (g & 1) * 8;
        s.q0 = *(const float4*)p;
        s.q1 = *(const float4*)(p + 4);
        s.w  = ewB[eidx];
        return s;
    };
    auto run_tile = [&](const TS& st) {
        // B-frag: e_in^T (k 0..31) straight from registers
        v8h B0 = mkv8h(pkh(st.q0.x, st.q0.y), pkh(st.q0.z, st.q0.w),
                       pkh(st.q1.x, st.q1.y), pkh(st.q1.z, st.q1.w));
        // layer 1: 4 MFMA; w-row + bias folded via VALU with LDS constants
        uint32_t dA[4], dB[4];
        #pragma unroll
        for (int mt = 0; mt < 4; mt++) {
            v4f D = {0.f, 0.f, 0.f, 0.f};
            D = __builtin_amdgcn_mfma_f32_16x16x32_f16(A0w1[mt], B0, D, 0, 0, 0);
            v4f wf = *(const v4f*)&sFold[mt][g][0];
            v4f bf = *(const v4f*)&sFold[mt][g][4];
            float d0 = fmaf(wf[0], st.w, D[0] + bf[0]);
            float d1 = fmaf(wf[1], st.w, D[1] + bf[1]);
            float d2 = fmaf(wf[2], st.w, D[2] + bf[2]);
            float d3 = fmaf(wf[3], st.w, D[3] + bf[3]);
            dA[mt] = pkh(fmaxf(d0, 0.f), fmaxf(d1, 0.f));
            dB[mt] = pkh(fmaxf(d2, 0.f), fmaxf(d3, 0.f));
        }
        // transition 1: permute BOTH mt candidates, select on dest lane
        uint32_t pa1A0 = (uint32_t)__builtin_amdgcn_ds_bpermute(a1, (int)dA[0]);
        uint32_t pa1A1 = (uint32_t)__builtin_amdgcn_ds_bpermute(a1, (int)dA[1]);
        uint32_t pa1B0 = (uint32_t)__builtin_amdgcn_ds_bpermute(a1, (int)dB[0]);
        uint32_t pa1B1 = (uint32_t)__builtin_amdgcn_ds_bpermute(a1, (int)dB[1]);
        uint32_t pa2A0 = (uint32_t)__builtin_amdgcn_ds_bpermute(a2, (int)dA[0]);
        uint32_t pa2A1 = (uint32_t)__builtin_amdgcn_ds_bpermute(a2, (int)dA[1]);
        uint32_t pa2B0 = (uint32_t)__builtin_amdgcn_ds_bpermute(a2, (int)dB[0]);
        uint32_t pa2B1 = (uint32_t)__builtin_amdgcn_ds_bpermute(a2, (int)dB[1]);
        v8h B20 = mkv8h(glo ? pa1A0 : pa1A1, glo ? pa1B0 : pa1B1,
                        glo ? pa2A0 : pa2A1, glo ? pa2B0 : pa2B1);
        uint32_t qa1A2 = (uint32_t)__builtin_amdgcn_ds_bpermute(a1, (int)dA[2]);
        uint32_t qa1A3 = (uint32_t)__builtin_amdgcn_ds_bpermute(a1, (int)dA[3]);
        uint32_t qa1B2 = (uint32_t)__builtin_amdgcn_ds_bpermute(a1, (int)dB[2]);
        uint32_t qa1B3 = (uint32_t)__builtin_amdgcn_ds_bpermute(a1, (int)dB[3]);
        uint32_t qa2A2 = (uint32_t)__builtin_amdgcn_ds_bpermute(a2, (int)dA[2]);
        uint32_t qa2A3 = (uint32_t)__builtin_amdgcn_ds_bpermute(a2, (int)dA[3]);
        uint32_t qa2B2 = (uint32_t)__builtin_amdgcn_ds_bpermute(a2, (int)dB[2]);
        uint32_t qa2B3 = (uint32_t)__builtin_amdgcn_ds_bpermute(a2, (int)dB[3]);
        v8h B21 = mkv8h(glo ? qa1A2 : qa1A3, glo ? qa1B2 : qa1B3,
                        glo ? qa2A2 : qa2A3, glo ? qa2B2 : qa2B3);
        // layer 2: 4 MFMA, bias from LDS at pack time
        uint32_t dA2[2], dB2[2];
        #pragma unroll
        for (int mt = 0; mt < 2; mt++) {
            v4f D = {0.f, 0.f, 0.f, 0.f};
            D = __builtin_amdgcn_mfma_f32_16x16x32_f16(A0w2[mt], B20, D, 0, 0, 0);
            D = __builtin_amdgcn_mfma_f32_16x16x32_f16(A1w2[mt], B21, D, 0, 0, 0);
            v4f bf = *(const v4f*)&sb2f[mt][g][0];
            dA2[mt] = pkh(fmaxf(D[0] + bf[0], 0.f), fmaxf(D[1] + bf[1], 0.f));
            dB2[mt] = pkh(fmaxf(D[2] + bf[2], 0.f), fmaxf(D[3] + bf[3], 0.f));
        }
        // transition 2
        uint32_t ra1A0 = (uint32_t)__builtin_amdgcn_ds_bpermute(a1, (int)dA2[0]);
        uint32_t ra1A1 = (uint32_t)__builtin_amdgcn_ds_bpermute(a1, (int)dA2[1]);
        uint32_t ra1B0 = (uint32_t)__builtin_amdgcn_ds_bpermute(a1, (int)dB2[0]);
        uint32_t ra1B1 = (uint32_t)__builtin_amdgcn_ds_bpermute(a1, (int)dB2[1]);
        uint32_t ra2A0 = (uint32_t)__builtin_amdgcn_ds_bpermute(a2, (int)dA2[0]);
        uint32_t ra2A1 = (uint32_t)__builtin_amdgcn_ds_bpermute(a2, (int)dA2[1]);
        uint32_t ra2B0 = (uint32_t)__builtin_amdgcn_ds_bpermute(a2, (int)dB2[0]);
        uint32_t ra2B1 = (uint32_t)__builtin_amdgcn_ds_bpermute(a2, (int)dB2[1]);
        v8h B3 = mkv8h(glo ? ra1A0 : ra1A1, glo ? ra1B0 : ra1B1,
                       glo ? ra2A0 : ra2A1, glo ? ra2B0 : ra2B1);
        // layer 3: 4 MFMA, sigmoid, signed LDS scatter (stride-67 rows)
        float* sap = &sagg[0][0] + st.own * 67 + 4 * g;
        #pragma unroll
        for (int mt = 0; mt < 4; mt++) {
            v4f D = {0.f, 0.f, 0.f, 0.f};
            D = __builtin_amdgcn_mfma_f32_16x16x32_f16(A0w3[mt], B3, D, 0, 0, 0);
            v4f bf = *(const v4f*)&sb3f[mt][g][0];
            #pragma unroll
            for (int r = 0; r < 4; r++) {
                float s = st.sgn / (1.0f + __expf(-(D[r] + bf[r])));
                atomicAdd(sap + 16 * mt + r, s);          // ds_add_f32
            }
        }
    };

    int base = beg + wv * 32;

    TS sA{}, sB{};
    uint2 rA = make_uint2(SENTX, 0u), rB = make_uint2(SENTX, 0u);
    if (base < end) {
        rA = fetch_raw(base);
        rB = fetch_raw(base + 16);
        sA = stage(rA, base);
        sB = stage(rB, base + 16);
        rA = fetch_raw(base + 128);
        rB = fetch_raw(base + 144);
    }

    #pragma unroll 1
    while (base < end) {
        const int nbase = base + 128;
        TS nA{}, nB{};
        if (nbase < end) {
            nA = stage(rA, nbase);
            nB = stage(rB, nbase + 16);
            rA = fetch_raw(nbase + 128);
            rB = fetch_raw(nbase + 144);
        }
        run_tile(sA);
        run_tile(sB);
        sA = nA; sB = nB;
        base = nbase;
    }

    __syncthreads();

    // ---- fused node MLP: 65 -> 12 -> 1 ----
    if (tid < nvalid) {
        float nh[NHID];
        #pragma unroll
        for (int j = 0; j < NHID; j++) nh[j] = sb4[j];
        const float* ar = &sagg[tid][0];
        #pragma unroll
        for (int k = 0; k < EOUT; k++) {
            float v = ar[k];
            const float* wr = sW4 + k * NHID;
            #pragma unroll
            for (int j = 0; j < NHID; j++) nh[j] = fmaf(v, wr[j], nh[j]);
        }
        {
            float v = lp[(size_t)b * N_ + node0 + tid];
            const float* wr = sW4 + EOUT * NHID;
            #pragma unroll
            for (int j = 0; j < NHID; j++) nh[j] = fmaf(v, wr[j], nh[j]);
        }
        float acc = sb5v;
        #pragma unroll
        for (int j = 0; j < NHID; j++) acc = fmaf(fmaxf(nh[j], 0.f), sW5[j], acc);
        out[(size_t)b * N_ + node0 + tid] = 1.0f / (1.0f + __expf(-acc));
    }
}

// ---------------- launch ----------------

extern "C" void kernel_launch(void* const* d_in, const int* in_sizes, int n_in,
                              void* d_out, int out_size, void* d_ws, size_t ws_size,
                              hipStream_t stream)
{
    const float* nf   = (const float*)d_in[0];
    const float* ew   = (const float*)d_in[1];
    const float* lp   = (const float*)d_in[2];
    const int*   esrc = (const int*)d_in[3];
    const int*   etgt = (const int*)d_in[4];
    const float* W1 = (const float*)d_in[5],  *b1 = (const float*)d_in[6];
    const float* W2 = (const float*)d_in[7],  *b2 = (const float*)d_in[8];
    const float* W3 = (const float*)d_in[9],  *b3 = (const float*)d_in[10];
    const float* W4 = (const float*)d_in[11], *b4 = (const float*)d_in[12];
    const float* W5 = (const float*)d_in[13], *b5 = (const float*)d_in[14];

    float* out = (float*)d_out;
    char*  ws  = (char*)d_ws;

    int*   counts  = (int*)(ws + 0);
    int*   offsets = (int*)(ws + 4096);
    int*   cursors = (int*)(ws + 8192);
    uint2* entries = (uint2*)(ws + 16384);

    (void)hipMemsetAsync(counts, 0, 4096, stream);
    hist_kernel<<<HB, 256, 0, stream>>>(esrc, etgt, counts);
    scan_kernel<<<1, 1024, 0, stream>>>(counts, offsets, cursors);
    fill_kernel<<<HB, 256, 0, stream>>>(esrc, etgt, cursors, entries);

    dim3 cg(NCHUNK, B_);
    chunk_kernel<<<cg, 256, 0, stream>>>(nf, ew, lp, entries, offsets,
                                         W1, b1, W2, b2, W3, b3,
                                         W4, b4, W5, b5, out);
}